// Round 2
// baseline (199.670 us; speedup 1.0000x reference)
//
#include <hip/hip_runtime.h>

// LocalMean: 5x5 box filter, reflect padding, on (32,3,512,512) fp32.
// Separable: horizontal 5-sum per row (from 3 aligned float4 loads),
// vertical 5-sum via shift-register rolling over rows.
// R1: SUBROWS 32->8 to fix occupancy (23% -> target 70%+); warm-up
// re-reads are L2/L3 hits (input is L3-resident, FETCH_SIZE showed 55MB).

constexpr int H = 512;
constexpr int W = 512;
constexpr int ROWS = 16;     // rows per block
constexpr int SUBROWS = 8;   // rows per thread (threadIdx.y splits ROWS)
constexpr int QX = W / 4;    // 128 float4 quads per row

// Horizontal 5-tap sums for one x-quad of (reflected) row yy.
__device__ __forceinline__ float4 row_hsum(const float* __restrict__ pin, int yy, int q) {
    // reflect in y: -1->1, -2->2 ; 512->510, 513->509
    if (yy < 0) yy = -yy;
    if (yy >= H) yy = 2 * H - 2 - yy;
    const float4* r = (const float4*)(pin + (size_t)yy * W);
    float4 cur = r[q];
    float pz, pw, nx, ny;
    if (q > 0) { float4 p = r[q - 1]; pz = p.z; pw = p.w; }
    else       { pz = cur.z; pw = cur.y; }   // reflect: e[-2]=e[2], e[-1]=e[1]
    if (q < QX - 1) { float4 n = r[q + 1]; nx = n.x; ny = n.y; }
    else            { nx = cur.z; ny = cur.y; } // reflect: e[512]=e[510], e[513]=e[509]
    float s = cur.x + cur.y + cur.z + cur.w;
    float4 hs;
    hs.x = (s - cur.w) + pz + pw;   // x-2..x+2
    hs.y = s + pw;                  // x-1..x+3
    hs.z = s + nx;                  // x  ..x+4
    hs.w = (s - cur.x) + nx + ny;   // x+1..x+5
    return hs;
}

__global__ __launch_bounds__(256) void localmean_kernel(const float* __restrict__ in,
                                                        float* __restrict__ out) {
    const int chunks = H / ROWS;                       // 32
    const int plane  = blockIdx.x / chunks;            // 0..95 (n*c)
    const int chunk  = blockIdx.x % chunks;
    const int y0     = chunk * ROWS + threadIdx.y * SUBROWS;
    const int q      = threadIdx.x;                    // x-quad, 0..127

    const float* pin  = in  + (size_t)plane * H * W;
    float*       pout = out + (size_t)plane * H * W;

    // warm-up: rows y0-2 .. y0+1
    float4 h0 = row_hsum(pin, y0 - 2, q);
    float4 h1 = row_hsum(pin, y0 - 1, q);
    float4 h2 = row_hsum(pin, y0,     q);
    float4 h3 = row_hsum(pin, y0 + 1, q);

    const float inv = 1.0f / 25.0f;
    #pragma unroll
    for (int y = y0; y < y0 + SUBROWS; ++y) {
        float4 h4 = row_hsum(pin, y + 2, q);
        float4 v;
        v.x = (h0.x + h1.x + h2.x + h3.x + h4.x) * inv;
        v.y = (h0.y + h1.y + h2.y + h3.y + h4.y) * inv;
        v.z = (h0.z + h1.z + h2.z + h3.z + h4.z) * inv;
        v.w = (h0.w + h1.w + h2.w + h3.w + h4.w) * inv;
        ((float4*)(pout + (size_t)y * W))[q] = v;
        h0 = h1; h1 = h2; h2 = h3; h3 = h4;   // shift register (renamed under unroll)
    }
}

extern "C" void kernel_launch(void* const* d_in, const int* in_sizes, int n_in,
                              void* d_out, int out_size, void* d_ws, size_t ws_size,
                              hipStream_t stream) {
    const float* in = (const float*)d_in[0];
    float* out = (float*)d_out;
    const int planes = in_sizes[0] / (H * W);          // 32*3 = 96
    dim3 grid(planes * (H / ROWS));                    // 3072 blocks
    dim3 block(QX, ROWS / SUBROWS);                    // (128,2) = 256 threads
    localmean_kernel<<<grid, block, 0, stream>>>(in, out);
}

// Round 3
// 173.435 us; speedup vs baseline: 1.1513x; 1.1513x over previous
//
#include <hip/hip_runtime.h>

// LocalMean: 5x5 box filter, reflect padding, (32,3,512,512) fp32.
// R2: LDS-staged. R1 showed VGPR=28 -> compiler serialized per-row loads
// (one row of MLP per wave), capping BW at 2.1 TB/s regardless of occupancy.
// Now: copy-like load phase (10 independent coalesced float4 loads/thread,
// reg-staged into 40KB LDS), then rolling 5-row sums from LDS.

constexpr int H = 512;
constexpr int W = 512;
constexpr int ROWS = 16;            // output rows per block
constexpr int LROWS = ROWS + 4;     // 20 staged rows (2-row halo each side)
constexpr int QX = W / 4;           // 128 float4 quads per row

// 5-tap horizontal sums for quad q of one LDS row.
__device__ __forceinline__ float4 hsum_row(const float* __restrict__ row, int q) {
    float4 cur = *(const float4*)(row + q * 4);
    float2 lf, rt;
    if (q > 0)      lf = *(const float2*)(row + q * 4 - 2);
    else            { lf.x = cur.z; lf.y = cur.y; }      // reflect: e[-2]=e[2], e[-1]=e[1]
    if (q < QX - 1) rt = *(const float2*)(row + q * 4 + 4);
    else            { rt.x = cur.z; rt.y = cur.y; }      // reflect: e[512]=e[510], e[513]=e[509]
    float s = cur.x + cur.y + cur.z + cur.w;
    float4 h;
    h.x = (s - cur.w) + lf.x + lf.y;   // x-2..x+2
    h.y = s + lf.y;                    // x-1..x+3
    h.z = s + rt.x;                    // x  ..x+4
    h.w = (s - cur.x) + rt.x + rt.y;   // x+1..x+5
    return h;
}

__global__ __launch_bounds__(256) void localmean_kernel(const float* __restrict__ in,
                                                        float* __restrict__ out) {
    __shared__ float lds[LROWS][W];                     // 40 KB -> 4 blocks/CU

    const int chunks = H / ROWS;                        // 32
    const int plane  = blockIdx.x / chunks;             // 0..95
    const int chunk  = blockIdx.x % chunks;
    const int y0     = chunk * ROWS;
    const int t      = threadIdx.x;

    const float* pin  = in  + (size_t)plane * H * W;
    float*       pout = out + (size_t)plane * H * W;

    // ---- load phase: 20 rows x 128 quads = 2560 float4, 10 per thread.
    // All 10 loads independent & coalesced (1KB/wave/instr) -> full MLP.
    float4 buf[10];
    #pragma unroll
    for (int i = 0; i < 10; ++i) {
        int idx = i * 256 + t;          // quad index in tile
        int r   = idx >> 7;             // staged row 0..19 (uniform per wave)
        int q   = idx & 127;
        int gy  = y0 - 2 + r;           // reflect in y
        gy = (gy < 0) ? -gy : gy;
        gy = (gy >= H) ? (2 * H - 2 - gy) : gy;
        buf[i] = *(const float4*)(pin + (size_t)gy * W + q * 4);
    }
    #pragma unroll
    for (int i = 0; i < 10; ++i) {
        int idx = i * 256 + t;
        *(float4*)(&lds[0][0] + idx * 4) = buf[i];
    }
    __syncthreads();

    // ---- compute phase: ty in {0,1} owns 8 output rows; roll 5 h-sums.
    const int tx = t & 127;
    const int ty = t >> 7;
    const float* base = &lds[ty * 8][0];

    float4 h0 = hsum_row(base + 0 * W, tx);
    float4 h1 = hsum_row(base + 1 * W, tx);
    float4 h2 = hsum_row(base + 2 * W, tx);
    float4 h3 = hsum_row(base + 3 * W, tx);

    const float inv = 1.0f / 25.0f;
    #pragma unroll
    for (int j = 0; j < 8; ++j) {
        float4 h4 = hsum_row(base + (j + 4) * W, tx);
        float4 v;
        v.x = (h0.x + h1.x + h2.x + h3.x + h4.x) * inv;
        v.y = (h0.y + h1.y + h2.y + h3.y + h4.y) * inv;
        v.z = (h0.z + h1.z + h2.z + h3.z + h4.z) * inv;
        v.w = (h0.w + h1.w + h2.w + h3.w + h4.w) * inv;
        ((float4*)(pout + (size_t)(y0 + ty * 8 + j) * W))[tx] = v;
        h0 = h1; h1 = h2; h2 = h3; h3 = h4;
    }
}

extern "C" void kernel_launch(void* const* d_in, const int* in_sizes, int n_in,
                              void* d_out, int out_size, void* d_ws, size_t ws_size,
                              hipStream_t stream) {
    const float* in = (const float*)d_in[0];
    float* out = (float*)d_out;
    const int planes = in_sizes[0] / (H * W);           // 96
    dim3 grid(planes * (H / ROWS));                     // 3072 blocks
    dim3 block(256);
    localmean_kernel<<<grid, block, 0, stream>>>(in, out);
}